// Round 15
// baseline (232.434 us; speedup 1.0000x reference)
//
#include <hip/hip_runtime.h>
#include <hip/hip_bf16.h>

// ---------------------------------------------------------------------------
// SeqAttnMatch, fp32 in/out, B=64, L1=L2=1024, H=128.  TWO launches.
// proj (1024 blocks = 512 X-tiles + 512 Y-tiles, 256 thr): each block owns a
//   full 128-row tile, loads raw fp32 ONCE, computes BOTH h-halves
//   (W inline-split into LDS in two 32KB chunks, chunk 2 staged behind the
//   half-0 epilogue). Coalesced h8v dumps via padded sE. Y blocks emit the
//   YTsw transpose image from raw regs. Blocks 0..63 self-OR the mask and
//   normalize it (no prep dependency).
// attn (r10-proven, untouched): 512x512, 8-wave shared staged j-tiles.
// ---------------------------------------------------------------------------

typedef __attribute__((ext_vector_type(8))) short    s8v;  // 8 bf16 = 16B
typedef __attribute__((ext_vector_type(8))) _Float16 h8v;  // 8 f16 = 16B
typedef __attribute__((ext_vector_type(4))) _Float16 h4v;  // 4 f16 = 8B
typedef __attribute__((ext_vector_type(4))) float    f4v;

#define BDIM 256

__device__ __forceinline__ f4v mfma_bf16(s8v a, s8v b, f4v c) {
    return __builtin_amdgcn_mfma_f32_16x16x32_bf16(a, b, c, 0, 0, 0);
}
__device__ __forceinline__ f4v mfma_f16(h8v a, h8v b, f4v c) {
    return __builtin_amdgcn_mfma_f32_16x16x32_f16(a, b, c, 0, 0, 0);
}
// truncation split: v = bf16(hi) + bf16(lo) + O(2^-17 v). 3 VALU ops, no RNE.
__device__ __forceinline__ void tsplit(float v, short& hi, short& lo) {
    unsigned b = __builtin_bit_cast(unsigned, v);
    unsigned hb = b & 0xFFFF0000u;
    float res = v - __builtin_bit_cast(float, hb);
    hi = (short)(hb >> 16);
    lo = (short)(__builtin_bit_cast(unsigned, res) >> 16);
}

typedef const __attribute__((address_space(1))) unsigned int gu32;
typedef __attribute__((address_space(3))) unsigned int lu32;
// async 16B/lane global->LDS; LDS dest = wave-uniform base + lane*16 (m97/m104)
__device__ __forceinline__ void gld_lds16(const void* g, void* l) {
    __builtin_amdgcn_global_load_lds((gu32*)g, (lu32*)l, 16, 0, 0);
}

// ---------------------------------------------------------------------------
// proj: one block per 128-row tile. Both h-halves from one raw load.
// ---------------------------------------------------------------------------
__global__ __launch_bounds__(BDIM, 3) void proj_kernel(
    const float* __restrict__ X, const float* __restrict__ Y,
    const float* __restrict__ W, const float* __restrict__ bias,
    const unsigned int* __restrict__ mraw, unsigned char* __restrict__ nm,
    _Float16* __restrict__ XPf, _Float16* __restrict__ YPsw,
    _Float16* __restrict__ YTsw)
{
    __shared__ short sW[2][64][128];      // 32KB: current W chunk (hi/lo planes)
    __shared__ _Float16 sE[128 * 72];     // 18KB: padded epilogue tile
    __shared__ unsigned sOr[2];

    const int gid = blockIdx.x;
    const bool isY = (gid >= 512);
    const int local = isY ? gid - 512 : gid;
    const float* src = isY ? Y : X;
    const int row0 = local * 128;
    const int t = threadIdx.x, w = t >> 6, lane = t & 63, c = lane & 15, q = lane >> 4;

    if (t == 0) { sOr[0] = 0u; sOr[1] = 0u; }

    // stage W chunk 0 (rows 0..63), inline trunc-split, baked swizzle
#pragma unroll 4
    for (int i = 0; i < 32; ++i) {
        int idx = t + i * BDIM;                 // 0..8191
        int rr = idx >> 7, c2 = idx & 127;
        short hi, lo; tsplit(W[rr * 128 + c2], hi, lo);
        int cs = (((c2 >> 3) ^ (rr & 15)) << 3) | (c2 & 7);
        sW[0][rr][cs] = hi;
        sW[1][rr][cs] = lo;
    }

    // raw tile loads, once (shared by both halves + YT emission)
    f4v rawA[2][4], rawB[2][4];
#pragma unroll
    for (int set = 0; set < 2; ++set) {
        const float* xr = src + (size_t)(row0 + w * 32 + set * 16 + c) * 128;
#pragma unroll
        for (int ks = 0; ks < 4; ++ks) {
            rawA[set][ks] = *(const f4v*)&xr[ks * 32 + q * 8];
            rawB[set][ks] = *(const f4v*)&xr[ks * 32 + q * 8 + 4];
        }
    }
    __syncthreads();   // B1: chunk0 staged

    f4v zero = {0.f, 0.f, 0.f, 0.f};
    h4v res[2][4];

    // ---- half 0 compute ----
#pragma unroll
    for (int set = 0; set < 2; ++set) {
        s8v ah[4], al[4];
#pragma unroll
        for (int ks = 0; ks < 4; ++ks)
            for (int k = 0; k < 4; ++k) {
                short hh, ll;
                tsplit(rawA[set][ks][k], hh, ll); ah[ks][k] = hh;     al[ks][k] = ll;
                tsplit(rawB[set][ks][k], hh, ll); ah[ks][4 + k] = hh; al[ks][4 + k] = ll;
            }
        f4v acc[4];
        for (int n = 0; n < 4; ++n) acc[n] = zero;
#pragma unroll
        for (int ks = 0; ks < 4; ++ks) {
            s8v bh[4], bl[4];
            for (int nt = 0; nt < 4; ++nt) {
                int cs = (((ks * 4 + q) ^ c) << 3);
                bh[nt] = *(const s8v*)&sW[0][nt * 16 + c][cs];
                bl[nt] = *(const s8v*)&sW[1][nt * 16 + c][cs];
            }
            for (int nt = 0; nt < 4; ++nt) {
                acc[nt] = mfma_bf16(ah[ks], bh[nt], acc[nt]);
                acc[nt] = mfma_bf16(al[ks], bh[nt], acc[nt]);
                acc[nt] = mfma_bf16(ah[ks], bl[nt], acc[nt]);
            }
        }
        for (int nt = 0; nt < 4; ++nt) {
            float bv = bias[nt * 16 + c];
            for (int r = 0; r < 4; ++r)
                res[set][nt][r] = (_Float16)fmaxf(acc[nt][r] + bv, 0.0f);
        }
    }
    __syncthreads();   // B2: all chunk0 reads done

    // stage W chunk 1 (rows 64..127) + write sE half 0
#pragma unroll 4
    for (int i = 0; i < 32; ++i) {
        int idx = t + i * BDIM;
        int rr = idx >> 7, c2 = idx & 127;
        short hi, lo; tsplit(W[(64 + rr) * 128 + c2], hi, lo);
        int cs = (((c2 >> 3) ^ (rr & 15)) << 3) | (c2 & 7);
        sW[0][rr][cs] = hi;
        sW[1][rr][cs] = lo;
    }
#pragma unroll
    for (int set = 0; set < 2; ++set)
        for (int nt = 0; nt < 4; ++nt)
            for (int r = 0; r < 4; ++r) {
                int lr = w * 32 + set * 16 + q * 4 + r;
                int col;
                if (isY) col = (((2 * nt + (c >> 3)) ^ (lr & 7)) << 3) | (c & 7);
                else     col = nt * 16 + c;
                sE[lr * 72 + col] = res[set][nt][r];
            }
    __syncthreads();   // B3: chunk1 + sE half0 ready

    // dump half 0 (concurrent with half-1 compute below in this phase)
    if (!isY) {
        for (int i = 0; i < 4; ++i) {
            int idx = t + i * BDIM;
            int lr = idx >> 3, pos = (idx & 7) * 8;
            *(h8v*)(XPf + (size_t)(row0 + lr) * 128 + pos) =
                *(const h8v*)(sE + lr * 72 + pos);
        }
    } else {
        for (int i = 0; i < 4; ++i) {
            int idx = t + i * BDIM;
            int lr = idx >> 3, pos = (idx & 7) * 8;
            *(h8v*)(YPsw + (size_t)((row0 + lr) >> 6) * 8192
                    + (size_t)(lr & 63) * 128 + pos) =
                *(const h8v*)(sE + lr * 72 + pos);
        }
    }

    // ---- half 1 compute (A-frags recomputed from raw; B from chunk1) ----
#pragma unroll
    for (int set = 0; set < 2; ++set) {
        s8v ah[4], al[4];
#pragma unroll
        for (int ks = 0; ks < 4; ++ks)
            for (int k = 0; k < 4; ++k) {
                short hh, ll;
                tsplit(rawA[set][ks][k], hh, ll); ah[ks][k] = hh;     al[ks][k] = ll;
                tsplit(rawB[set][ks][k], hh, ll); ah[ks][4 + k] = hh; al[ks][4 + k] = ll;
            }
        f4v acc[4];
        for (int n = 0; n < 4; ++n) acc[n] = zero;
#pragma unroll
        for (int ks = 0; ks < 4; ++ks) {
            s8v bh[4], bl[4];
            for (int nt = 0; nt < 4; ++nt) {
                int cs = (((ks * 4 + q) ^ c) << 3);
                bh[nt] = *(const s8v*)&sW[0][nt * 16 + c][cs];
                bl[nt] = *(const s8v*)&sW[1][nt * 16 + c][cs];
            }
            for (int nt = 0; nt < 4; ++nt) {
                acc[nt] = mfma_bf16(ah[ks], bh[nt], acc[nt]);
                acc[nt] = mfma_bf16(al[ks], bh[nt], acc[nt]);
                acc[nt] = mfma_bf16(ah[ks], bl[nt], acc[nt]);
            }
        }
        for (int nt = 0; nt < 4; ++nt) {
            float bv = bias[64 + nt * 16 + c];
            for (int r = 0; r < 4; ++r)
                res[set][nt][r] = (_Float16)fmaxf(acc[nt][r] + bv, 0.0f);
        }
    }
    __syncthreads();   // B4: sE dump done; chunk1 reads done

    // write sE half 1 ; Y blocks also write YT image into the dead sW arena
#pragma unroll
    for (int set = 0; set < 2; ++set)
        for (int nt = 0; nt < 4; ++nt)
            for (int r = 0; r < 4; ++r) {
                int lr = w * 32 + set * 16 + q * 4 + r;
                int col;
                if (isY) col = (((2 * nt + (c >> 3)) ^ (lr & 7)) << 3) | (c & 7);
                else     col = nt * 16 + c;
                sE[lr * 72 + col] = res[set][nt][r];
            }
    if (isY) {
        _Float16* sT = (_Float16*)&sW[0][0][0];   // [2 tiles][128 h][64 swz j]
#pragma unroll
        for (int set = 0; set < 2; ++set) {
            int row = w * 32 + set * 16 + c;      // local j 0..127
            int tile = row >> 6, j6 = row & 63;
            int jlo = j6 & 7, jhb = (j6 >> 3);
#pragma unroll
            for (int ks = 0; ks < 4; ++ks)
                for (int k = 0; k < 4; ++k) {
                    int h = ks * 32 + q * 8 + k;
                    sT[tile * 8192 + h * 64 + (((jhb ^ (h & 7)) << 3) | jlo)] =
                        (_Float16)rawA[set][ks][k];
                    int h2 = h + 4;
                    sT[tile * 8192 + h2 * 64 + (((jhb ^ (h2 & 7)) << 3) | jlo)] =
                        (_Float16)rawB[set][ks][k];
                }
        }
    }
    __syncthreads();   // B5

    // dump half 1 ; Y blocks dump YT (2 adjacent j-tiles, linear)
    if (!isY) {
        for (int i = 0; i < 4; ++i) {
            int idx = t + i * BDIM;
            int lr = idx >> 3, pos = (idx & 7) * 8;
            *(h8v*)(XPf + (size_t)(row0 + lr) * 128 + 64 + pos) =
                *(const h8v*)(sE + lr * 72 + pos);
        }
    } else {
        for (int i = 0; i < 4; ++i) {
            int idx = t + i * BDIM;
            int lr = idx >> 3, pos = (idx & 7) * 8;
            *(h8v*)(YPsw + (size_t)((row0 + lr) >> 6) * 8192
                    + (size_t)(lr & 63) * 128 + 64 + pos) =
                *(const h8v*)(sE + lr * 72 + pos);
        }
        const _Float16* sT = (const _Float16*)&sW[0][0][0];
        _Float16* dst = YTsw + (size_t)(local * 2) * 8192;
        for (int i = 0; i < 8; ++i) {
            int idx = t + i * BDIM;               // 0..2047
            *(h8v*)(dst + idx * 8) = *(const h8v*)(sT + idx * 8);
        }
    }

    // ---- mask normalize (blocks 0..63, self-contained OR-detect) ----
    if (gid < 64) {
        unsigned oa = 0u, oo = 0u;
        for (int i = t; i < 16384; i += BDIM) {
            unsigned v = mraw[i];
            oa |= v;
            if (i & 1) oo |= v;
        }
        atomicOr(&sOr[0], oa);
        atomicOr(&sOr[1], oo);
        __syncthreads();
        const unsigned orv = sOr[0], oro = sOr[1];
        int mode;  // 0 = 4B stride, 1 = uint8, 2 = 2B stride, 3 = int64
        if (orv <= 1u)                       mode = (orv == 1u && oro == 0u) ? 3 : 0;
        else if ((orv & 0xFEFEFEFEu) == 0u)  mode = 1;
        else if ((orv & 0x0000FFFFu) == 0u)  mode = 0;
        else                                 mode = 2;
        const unsigned char*  b8  = (const unsigned char*)mraw;
        const unsigned short* b16 = (const unsigned short*)mraw;
        const int base = gid * 1024;
        for (int i = t; i < 1024; i += BDIM) {
            int j = base + i;
            unsigned v;
            if (mode == 0)      v = mraw[j];
            else if (mode == 1) v = b8[j];
            else if (mode == 2) v = b16[j];
            else                v = mraw[2 * j] | mraw[2 * j + 1];
            nm[j] = v ? 1 : 0;
        }
    }
}

// ---------------------------------------------------------------------------
// attn (r10-proven, unchanged): 512 blocks = 8 xcd x 8 itile(128) x 8 batch.
// 8 waves share one double-buffered staged j-tile pair via global_load_lds;
// flat XOR-swizzled sP; LDS 81920B -> 2 blocks/CU = 16 waves/CU.
// ---------------------------------------------------------------------------
__global__ __launch_bounds__(512, 4) void attn_kernel(
    const _Float16* __restrict__ YPsw, const _Float16* __restrict__ YTsw,
    const unsigned char* __restrict__ nmask,
    const _Float16* __restrict__ XPf, float* __restrict__ out)
{
    __shared__ _Float16 sTile[2][16384];  // [buf]: [0..8191]=YP, [8192..]=YT
    __shared__ _Float16 sP[128 * 64];     // flat, chunk ck at ck^(row&7)

    const int id = blockIdx.x;
    const int xcd = id & 7, rest = id >> 3;
    const int ibase = (rest & 7) * 128;
    const int b = xcd + 8 * (rest >> 3);        // batch 0..63
    const int t = threadIdx.x, wave = t >> 6, lane = t & 63;
    const int c = lane & 15, q = lane >> 4;
    const int mrow = b * 1024;

    h8v afrag[4];
    {
        const _Float16* xr = XPf + (size_t)(mrow + ibase + wave * 16 + c) * 128;
        for (int ks = 0; ks < 4; ++ks)
            afrag[ks] = *(const h8v*)&xr[ks * 32 + q * 8];
    }

    const char* gYP = (const char*)(YPsw + (size_t)b * 16 * 8192);
    const char* gYT = (const char*)(YTsw + (size_t)b * 16 * 8192);
    const int soff = wave * 1024 + lane * 16;   // linear copy offsets

    // prologue: stage j-tile 0 into buffer 0 (drains at first barrier)
    {
        char* lp = (char*)&sTile[0][0]    + wave * 1024;
        char* lt = (char*)&sTile[0][8192] + wave * 1024;
        for (int i = 0; i < 2; ++i) {
            gld_lds16(gYP + soff + i * 8192, lp + i * 8192);
            gld_lds16(gYT + soff + i * 8192, lt + i * 8192);
        }
    }

    // mask words for j-tile 0 (byte r = j = nt*16 + q*4 + r)
    unsigned mw[4];
    for (int nt = 0; nt < 4; ++nt)
        mw[nt] = *(const unsigned*)(nmask + mrow + nt * 16 + q * 4);

    f4v zero = {0.f, 0.f, 0.f, 0.f};
    float m_s = -INFINITY, l_s = 0.f;     // per-lane: row i = c (of wave's slice)
    f4v o[8];
    for (int h = 0; h < 8; ++h) o[h] = zero;

    const int srcbase = (lane & 48) + ((lane >> 4) << 2);  // shfl src for i=q*4+r
    const int cb = q ^ (c & 7);                            // QK chunk swizzle base
    const int prow = (wave * 16 + c) * 64;                 // sP row base (f16 elems)
    const int pwofs = (q & 1) * 4;                         // within-chunk write half

    __syncthreads();   // tile 0 staged

    int cur = 0;
    for (int jt = 0; jt < 16; ++jt) {
        const int jbase = jt * 64;
        const int nx = cur ^ 1;

        // stage jt+1 into buffer nx: issued now, drains at this iter's barrier
        if (jt < 15) {
            const char* gp = gYP + (size_t)(jt + 1) * 16384;
            const char* gt = gYT + (size_t)(jt + 1) * 16384;
            char* lp = (char*)&sTile[nx][0]    + wave * 1024;
            char* lt = (char*)&sTile[nx][8192] + wave * 1024;
            for (int i = 0; i < 2; ++i) {
                gld_lds16(gp + soff + i * 8192, lp + i * 8192);
                gld_lds16(gt + soff + i * 8192, lt + i * 8192);
            }
        }

        // QK swapped: D[j][i]; A-frags from swizzled sYP (conflict-free b128)
        f4v s[4];
        __builtin_amdgcn_s_setprio(1);
        for (int nt = 0; nt < 4; ++nt) {
            const _Float16* rp = &sTile[cur][0] + (nt * 16 + c) * 128;
            h8v f0 = *(const h8v*)(rp + ((cb ^ 0) << 3));
            h8v f1 = *(const h8v*)(rp + ((cb ^ 4) << 3));
            h8v f2 = *(const h8v*)(rp + ((cb ^ 8) << 3));
            h8v f3 = *(const h8v*)(rp + ((cb ^ 12) << 3));
            f4v acc = zero;
            acc = mfma_f16(f0, afrag[0], acc);
            acc = mfma_f16(f1, afrag[1], acc);
            acc = mfma_f16(f2, afrag[2], acc);
            acc = mfma_f16(f3, afrag[3], acc);
            s[nt] = acc;
        }
        __builtin_amdgcn_s_setprio(0);

        // mask: byte r of mw[nt] set -> j = nt*16 + q*4 + r is padding
        for (int nt = 0; nt < 4; ++nt)
            for (int r = 0; r < 4; ++r)
                if ((mw[nt] >> (r * 8)) & 0xFFu) s[nt][r] = -1e30f;

        // in-register row max (row i=c), then 2 cross-lane steps over q-group
        float mx = fmaxf(
            fmaxf(fmaxf(fmaxf(s[0][0], s[0][1]), fmaxf(s[0][2], s[0][3])),
                  fmaxf(fmaxf(s[1][0], s[1][1]), fmaxf(s[1][2], s[1][3]))),
            fmaxf(fmaxf(fmaxf(s[2][0], s[2][1]), fmaxf(s[2][2], s[2][3])),
                  fmaxf(fmaxf(s[3][0], s[3][1]), fmaxf(s[3][2], s[3][3]))));
        mx = fmaxf(mx, __shfl_xor(mx, 16, 64));
        mx = fmaxf(mx, __shfl_xor(mx, 32, 64));
        float mnew = fmaxf(m_s, mx);
        float alpha = __expf(m_s - mnew);   // expf(-inf)=0 on first tile
        m_s = mnew;

        // P in f16 (masked -> exactly 0); row-sum in-register + 2 cross-lane;
        // packed b64 write: chunk 2nt+(q>>1) at swizzled position ^(c&7)
        float rsum = 0.f;
        for (int nt = 0; nt < 4; ++nt) {
            h4v ph4;
            for (int r = 0; r < 4; ++r) {
                float p = ((mw[nt] >> (r * 8)) & 0xFFu) ? 0.f
                          : __expf(s[nt][r] - mnew);
                _Float16 ph = (_Float16)p;
                rsum += (float)ph;
                ph4[r] = ph;
            }
            int ck = (2 * nt + (q >> 1)) ^ (c & 7);
            *(h4v*)&sP[prow + ck * 8 + pwofs] = ph4;
        }
        rsum += __shfl_xor(rsum, 16, 64);
        rsum += __shfl_xor(rsum, 32, 64);
        l_s = l_s * alpha + rsum;

        // mask refill for jt+1 (old mw fully consumed above)
        if (jt < 15) {
            const int jn = jbase + 64;
            for (int nt = 0; nt < 4; ++nt)
                mw[nt] = *(const unsigned*)(nmask + mrow + jn + nt * 16 + q * 4);
        }

        // alpha for D-layout rows i=q*4+r (src lane in same 16-group)
        float aD0 = __shfl(alpha, srcbase + 0, 64);
        float aD1 = __shfl(alpha, srcbase + 1, 64);
        float aD2 = __shfl(alpha, srcbase + 2, 64);
        float aD3 = __shfl(alpha, srcbase + 3, 64);
        for (int h = 0; h < 8; ++h) {
            o[h][0] *= aD0; o[h][1] *= aD1; o[h][2] *= aD2; o[h][3] *= aD3;
        }

        // PV: A from wave-private swizzled sP (in-order DS), B from sYT
        __builtin_amdgcn_s_setprio(1);
        for (int k2 = 0; k2 < 2; ++k2) {
            h8v a = *(const h8v*)&sP[prow + (((k2 << 2) + q) ^ (c & 7)) * 8];
            const _Float16* yt = &sTile[cur][8192];
            for (int hb = 0; hb < 8; ++hb) {
                h8v bb = *(const h8v*)(yt + (hb * 16 + c) * 64
                                       + ((((k2 << 2) + q) ^ (c & 7)) << 3));
                o[hb] = mfma_f16(a, bb, o[hb]);
            }
        }
        __builtin_amdgcn_s_setprio(0);

        __syncthreads();   // drains stage(jt+1); all reads of cur complete
        cur = nx;
    }

    // l for D-layout rows i=q*4+r, then divide + store
    float lD[4];
    lD[0] = __shfl(l_s, srcbase + 0, 64);
    lD[1] = __shfl(l_s, srcbase + 1, 64);
    lD[2] = __shfl(l_s, srcbase + 2, 64);
    lD[3] = __shfl(l_s, srcbase + 3, 64);
    for (int h = 0; h < 8; ++h) {
        for (int r = 0; r < 4; ++r) {
            float v = o[h][r] / lD[r];
            out[(size_t)(mrow + ibase + wave * 16 + q * 4 + r) * 128 + h * 16 + c] = v;
        }
    }
}

// ---------------------------------------------------------------------------
extern "C" void kernel_launch(void* const* d_in, const int* in_sizes, int n_in,
                              void* d_out, int out_size, void* d_ws, size_t ws_size,
                              hipStream_t stream) {
    const float* x    = (const float*)d_in[0];  // [64,1024,128] fp32
    const float* y    = (const float*)d_in[1];
    const unsigned int* mraw = (const unsigned int*)d_in[2];
    const float* W    = (const float*)d_in[3];  // [128,128] fp32
    const float* bias = (const float*)d_in[4];  // [128] fp32
    float* out = (float*)d_out;                 // [64,1024,128] fp32

    // ws: nmask 64KB | XPf 16MB | YPsw 16MB | YTsw 16MB
    unsigned char* nmask = (unsigned char*)d_ws;
    _Float16* XPf = (_Float16*)((char*)d_ws + 65536);
    _Float16* YPsw = XPf + (size_t)64 * 1024 * 128;
    _Float16* YTsw = YPsw + (size_t)64 * 1024 * 128;

    proj_kernel<<<1024, BDIM, 0, stream>>>(x, y, W, bias, mraw, nmask,
                                           XPf, YPsw, YTsw);
    attn_kernel<<<512, 512, 0, stream>>>(YPsw, YTsw, nmask, XPf, out);
}

// Round 16
// 195.387 us; speedup vs baseline: 1.1896x; 1.1896x over previous
//
#include <hip/hip_runtime.h>
#include <hip/hip_bf16.h>

// ---------------------------------------------------------------------------
// SeqAttnMatch, fp32 in/out, B=64, L1=L2=1024, H=128.
// prep (2 blocks): mask OR-detect -> orw; W trunc-split planes (baked swz).
// proj (1024 blocks, Y only): r14-proven split-bf16 GEMM -> YPsw + YTsw;
//   first 64 blocks normalize the mask. (X-projection moved into attn.)
// attn (512x512): r10-proven loop + one-time inline X-proj prologue that
//   computes afrag in-block (W planes staged into the sTile arena, sE
//   round-trip on sP) -- no XPf buffer at all.
// ---------------------------------------------------------------------------

typedef __attribute__((ext_vector_type(8))) short    s8v;  // 8 bf16 = 16B
typedef __attribute__((ext_vector_type(8))) _Float16 h8v;  // 8 f16 = 16B
typedef __attribute__((ext_vector_type(4))) _Float16 h4v;  // 4 f16 = 8B
typedef __attribute__((ext_vector_type(4))) float    f4v;

#define BDIM 256

__device__ __forceinline__ f4v mfma_bf16(s8v a, s8v b, f4v c) {
    return __builtin_amdgcn_mfma_f32_16x16x32_bf16(a, b, c, 0, 0, 0);
}
__device__ __forceinline__ f4v mfma_f16(h8v a, h8v b, f4v c) {
    return __builtin_amdgcn_mfma_f32_16x16x32_f16(a, b, c, 0, 0, 0);
}
// truncation split: v = bf16(hi) + bf16(lo) + O(2^-17 v). 3 VALU ops, no RNE.
__device__ __forceinline__ void tsplit(float v, short& hi, short& lo) {
    unsigned b = __builtin_bit_cast(unsigned, v);
    unsigned hb = b & 0xFFFF0000u;
    float res = v - __builtin_bit_cast(float, hb);
    hi = (short)(hb >> 16);
    lo = (short)(__builtin_bit_cast(unsigned, res) >> 16);
}

typedef const __attribute__((address_space(1))) unsigned int gu32;
typedef __attribute__((address_space(3))) unsigned int lu32;
// async 16B/lane global->LDS; LDS dest = wave-uniform base + lane*16 (m97/m104)
__device__ __forceinline__ void gld_lds16(const void* g, void* l) {
    __builtin_amdgcn_global_load_lds((gu32*)g, (lu32*)l, 16, 0, 0);
}

// ---------------------------------------------------------------------------
// prep: block 0 = mask OR-detect -> orw[0..1]; block 1 = W trunc-split.
// ---------------------------------------------------------------------------
__global__ __launch_bounds__(1024) void prep_kernel(
    const unsigned int* __restrict__ mraw, unsigned int* __restrict__ orw,
    const float* __restrict__ W, short* __restrict__ Whsw, short* __restrict__ Wlsw)
{
    if (blockIdx.x == 1) {
        for (int idx = threadIdx.x; idx < 16384; idx += 1024) {
            int r = idx >> 7, c = idx & 127;
            short hi, lo; tsplit(W[idx], hi, lo);
            int cs = (((c >> 3) ^ (r & 15)) << 3) | (c & 7);
            Whsw[r * 128 + cs] = hi;
            Wlsw[r * 128 + cs] = lo;
        }
        return;
    }
    __shared__ unsigned int sOrAll, sOrOdd;
    if (threadIdx.x == 0) { sOrAll = 0u; sOrOdd = 0u; }
    __syncthreads();
    unsigned int oa = 0u, oo = 0u;
    for (int i = threadIdx.x; i < 16384; i += 1024) {
        unsigned int v = mraw[i];
        oa |= v;
        if (i & 1) oo |= v;
    }
    atomicOr(&sOrAll, oa);
    atomicOr(&sOrOdd, oo);
    __syncthreads();
    if (threadIdx.x == 0) { orw[0] = sOrAll; orw[1] = sOrOdd; }
}

// ---------------------------------------------------------------------------
// proj (Y only): 1024 blocks = 512 tiles x 2 h-halves. r14-proven body.
// ---------------------------------------------------------------------------
__global__ __launch_bounds__(BDIM, 4) void proj_kernel(
    const float* __restrict__ Y,
    const short* __restrict__ Whsw, const short* __restrict__ Wlsw,
    const float* __restrict__ bias, const unsigned int* __restrict__ orw,
    const unsigned int* __restrict__ mraw, unsigned char* __restrict__ nm,
    _Float16* __restrict__ YPsw, _Float16* __restrict__ YTsw)
{
    __shared__ short sW[2][64][128];   // 32KB arena (W planes -> sE -> sT)

    const int gid = blockIdx.x;        // 0..1023
    const int row0 = (gid >> 1) * 128, h0 = (gid & 1) * 64;
    const int t = threadIdx.x, w = t >> 6, lane = t & 63, c = lane & 15, q = lane >> 4;

    {
        const short* g0 = Whsw + h0 * 128;
        const short* g1 = Wlsw + h0 * 128;
        short* l0 = &sW[0][0][0];
        short* l1 = &sW[1][0][0];
        for (int i = 0; i < 4; ++i) {
            int off = (t + i * BDIM) * 8;    // 0..8184
            *(s8v*)(l0 + off) = *(const s8v*)(g0 + off);
            *(s8v*)(l1 + off) = *(const s8v*)(g1 + off);
        }
    }

    // raw y loads for both sets, issued before the barrier (latency hidden)
    f4v rawA[2][4], rawB[2][4];
#pragma unroll
    for (int set = 0; set < 2; ++set) {
        const float* xr = Y + (size_t)(row0 + w * 32 + set * 16 + c) * 128;
#pragma unroll
        for (int ks = 0; ks < 4; ++ks) {
            rawA[set][ks] = *(const f4v*)&xr[ks * 32 + q * 8];
            rawB[set][ks] = *(const f4v*)&xr[ks * 32 + q * 8 + 4];
        }
    }
    __syncthreads();

    f4v zero = {0.f, 0.f, 0.f, 0.f};
    h4v res[2][4];
#pragma unroll
    for (int set = 0; set < 2; ++set) {
        s8v ah[4], al[4];
#pragma unroll
        for (int ks = 0; ks < 4; ++ks)
            for (int k = 0; k < 4; ++k) {
                short hh, ll;
                tsplit(rawA[set][ks][k], hh, ll); ah[ks][k] = hh;     al[ks][k] = ll;
                tsplit(rawB[set][ks][k], hh, ll); ah[ks][4 + k] = hh; al[ks][4 + k] = ll;
            }
        f4v acc[4];
        for (int n = 0; n < 4; ++n) acc[n] = zero;
#pragma unroll
        for (int ks = 0; ks < 4; ++ks) {
            s8v bh[4], bl[4];
            for (int nt = 0; nt < 4; ++nt) {
                int cs = (((ks * 4 + q) ^ c) << 3);       // baked swizzle
                bh[nt] = *(const s8v*)&sW[0][nt * 16 + c][cs];
                bl[nt] = *(const s8v*)&sW[1][nt * 16 + c][cs];
            }
            for (int nt = 0; nt < 4; ++nt) {
                acc[nt] = mfma_bf16(ah[ks], bh[nt], acc[nt]);
                acc[nt] = mfma_bf16(al[ks], bh[nt], acc[nt]);
                acc[nt] = mfma_bf16(ah[ks], bl[nt], acc[nt]);
            }
        }
        for (int nt = 0; nt < 4; ++nt) {
            float bv = bias[h0 + nt * 16 + c];
            for (int r = 0; r < 4; ++r)
                res[set][nt][r] = (_Float16)fmaxf(acc[nt][r] + bv, 0.0f);
        }
    }

    // ---- coalesced epilogue: padded LDS tile (aliased), then h8v dumps ----
    __syncthreads();                          // all sW reads done
    _Float16* sE = (_Float16*)&sW[0][0][0];   // [128][72] padded
#pragma unroll
    for (int set = 0; set < 2; ++set)
        for (int nt = 0; nt < 4; ++nt)
            for (int r = 0; r < 4; ++r) {
                int lr = w * 32 + set * 16 + q * 4 + r;
                int col = (((2 * nt + (c >> 3)) ^ (lr & 7)) << 3) | (c & 7);
                sE[lr * 72 + col] = res[set][nt][r];
            }
    __syncthreads();
    for (int i = 0; i < 4; ++i) {
        int idx = t + i * BDIM;
        int lr = idx >> 3, pos = (idx & 7) * 8;
        *(h8v*)(YPsw + (size_t)((row0 + lr) >> 6) * 8192
                + (size_t)(lr & 63) * 128 + h0 + pos) =
            *(const h8v*)(sE + lr * 72 + pos);
    }

    // ---- YT emission (h0==0 blocks): raw regs -> swizzled image ----
    if (h0 == 0) {
        __syncthreads();                          // sE dump reads done
        _Float16* sT = (_Float16*)&sW[0][0][0];   // [2 tiles][128 h][64 swz j]
#pragma unroll
        for (int set = 0; set < 2; ++set) {
            int row = w * 32 + set * 16 + c;      // local j 0..127
            int tile = row >> 6, j6 = row & 63;
            int jlo = j6 & 7, jhb = (j6 >> 3);
#pragma unroll
            for (int ks = 0; ks < 4; ++ks)
                for (int k = 0; k < 4; ++k) {
                    int h = ks * 32 + q * 8 + k;
                    sT[tile * 8192 + h * 64 + (((jhb ^ (h & 7)) << 3) | jlo)] =
                        (_Float16)rawA[set][ks][k];
                    int h2 = h + 4;
                    sT[tile * 8192 + h2 * 64 + (((jhb ^ (h2 & 7)) << 3) | jlo)] =
                        (_Float16)rawB[set][ks][k];
                }
        }
        __syncthreads();
        _Float16* dst = YTsw + (size_t)(row0 >> 6) * 8192;
        for (int i = 0; i < 8; ++i) {
            int idx = t + i * BDIM;               // 0..2047
            *(h8v*)(dst + idx * 8) = *(const h8v*)(sT + idx * 8);
        }
    }

    // ---- mask normalize (blocks 0..63, mode from orw) ----
    if (gid < 64) {
        const unsigned orv = orw[0], oro = orw[1];
        int mode;  // 0 = 4B stride, 1 = uint8, 2 = 2B stride, 3 = int64
        if (orv <= 1u)                       mode = (orv == 1u && oro == 0u) ? 3 : 0;
        else if ((orv & 0xFEFEFEFEu) == 0u)  mode = 1;
        else if ((orv & 0x0000FFFFu) == 0u)  mode = 0;
        else                                 mode = 2;
        const unsigned char*  b8  = (const unsigned char*)mraw;
        const unsigned short* b16 = (const unsigned short*)mraw;
        const int base = gid * 1024;
        for (int i = t; i < 1024; i += BDIM) {
            int j = base + i;
            unsigned v;
            if (mode == 0)      v = mraw[j];
            else if (mode == 1) v = b8[j];
            else if (mode == 2) v = b16[j];
            else                v = mraw[2 * j] | mraw[2 * j + 1];
            nm[j] = v ? 1 : 0;
        }
    }
}

// ---------------------------------------------------------------------------
// attn: r10-proven loop + inline X-proj prologue (no XPf).
// 512 blocks = 8 xcd x 8 itile(128) x 8 batch, 512 threads.
// ---------------------------------------------------------------------------
__global__ __launch_bounds__(512, 4) void attn_kernel(
    const float* __restrict__ X,
    const short* __restrict__ Whsw, const short* __restrict__ Wlsw,
    const float* __restrict__ bias,
    const _Float16* __restrict__ YPsw, const _Float16* __restrict__ YTsw,
    const unsigned char* __restrict__ nmask, float* __restrict__ out)
{
    __shared__ _Float16 sTile[2][16384];  // [buf]: [0..8191]=YP, [8192..]=YT
    __shared__ _Float16 sP[128 * 64];     // flat; prologue: sE [128][64]

    const int id = blockIdx.x;
    const int xcd = id & 7, rest = id >> 3;
    const int ibase = (rest & 7) * 128;
    const int b = xcd + 8 * (rest >> 3);        // batch 0..63
    const int t = threadIdx.x, wave = t >> 6, lane = t & 63;
    const int c = lane & 15, q = lane >> 4;
    const int mrow = b * 1024;

    f4v zero = {0.f, 0.f, 0.f, 0.f};

    // ================= inline X projection prologue =================
    // wave owns rows (ibase + wave*16 + 0..15); computes afrag directly.
    h8v afrag[4];
    {
        f4v rawA[4], rawB[4];
        const float* xr = X + (size_t)(mrow + ibase + wave * 16 + c) * 128;
#pragma unroll
        for (int ks = 0; ks < 4; ++ks) {
            rawA[ks] = *(const f4v*)&xr[ks * 32 + q * 8];
            rawB[ks] = *(const f4v*)&xr[ks * 32 + q * 8 + 4];
        }
        s8v ah[4], al[4];
#pragma unroll
        for (int ks = 0; ks < 4; ++ks)
            for (int k = 0; k < 4; ++k) {
                short hh, ll;
                tsplit(rawA[ks][k], hh, ll); ah[ks][k] = hh;     al[ks][k] = ll;
                tsplit(rawB[ks][k], hh, ll); ah[ks][4 + k] = hh; al[ks][4 + k] = ll;
            }

        short* sWp = (short*)&sTile[0][0];   // [2][64][128] W-plane arena
        _Float16* sE = sP;                   // [128][64] result half

#pragma unroll
        for (int half = 0; half < 2; ++half) {
            const int h0 = half * 64;
            // stage W planes for this half (512 thr x 2 x 16B x 2 iters)
            {
                const short* g0 = Whsw + h0 * 128;
                const short* g1 = Wlsw + h0 * 128;
                for (int i = 0; i < 2; ++i) {
                    int off = (t + i * 512) * 8;     // 0..8184
                    *(s8v*)(sWp + off)        = *(const s8v*)(g0 + off);
                    *(s8v*)(sWp + 8192 + off) = *(const s8v*)(g1 + off);
                }
            }
            __syncthreads();   // W staged (and sE free from prior half)

            f4v acc[4];
            for (int n = 0; n < 4; ++n) acc[n] = zero;
#pragma unroll
            for (int ks = 0; ks < 4; ++ks) {
                s8v bh[4], bl[4];
                for (int nt = 0; nt < 4; ++nt) {
                    int cs = (((ks * 4 + q) ^ c) << 3);
                    bh[nt] = *(const s8v*)&sWp[(nt * 16 + c) * 128 + cs];
                    bl[nt] = *(const s8v*)&sWp[8192 + (nt * 16 + c) * 128 + cs];
                }
                for (int nt = 0; nt < 4; ++nt) {
                    acc[nt] = mfma_bf16(ah[ks], bh[nt], acc[nt]);
                    acc[nt] = mfma_bf16(al[ks], bh[nt], acc[nt]);
                    acc[nt] = mfma_bf16(ah[ks], bl[nt], acc[nt]);
                }
            }
            __syncthreads();   // prior-half afrag reads done; sE writable
            for (int nt = 0; nt < 4; ++nt) {
                float bv = bias[h0 + nt * 16 + c];
                for (int r = 0; r < 4; ++r)
                    sE[(wave * 16 + q * 4 + r) * 64 + nt * 16 + c] =
                        (_Float16)fmaxf(acc[nt][r] + bv, 0.0f);
            }
            __syncthreads();   // sE complete
            afrag[half * 2]     = *(const h8v*)&sE[(wave * 16 + c) * 64 + q * 8];
            afrag[half * 2 + 1] = *(const h8v*)&sE[(wave * 16 + c) * 64 + 32 + q * 8];
        }
        __syncthreads();   // afrag reads done; sTile/sP free for attn
    }
    // ================= end prologue =================

    const char* gYP = (const char*)(YPsw + (size_t)b * 16 * 8192);
    const char* gYT = (const char*)(YTsw + (size_t)b * 16 * 8192);
    const int soff = wave * 1024 + lane * 16;   // linear copy offsets

    // prologue: stage j-tile 0 into buffer 0 (drains at first barrier)
    {
        char* lp = (char*)&sTile[0][0]    + wave * 1024;
        char* lt = (char*)&sTile[0][8192] + wave * 1024;
        for (int i = 0; i < 2; ++i) {
            gld_lds16(gYP + soff + i * 8192, lp + i * 8192);
            gld_lds16(gYT + soff + i * 8192, lt + i * 8192);
        }
    }

    // mask words for j-tile 0 (byte r = j = nt*16 + q*4 + r)
    unsigned mw[4];
    for (int nt = 0; nt < 4; ++nt)
        mw[nt] = *(const unsigned*)(nmask + mrow + nt * 16 + q * 4);

    float m_s = -INFINITY, l_s = 0.f;     // per-lane: row i = c (of wave's slice)
    f4v o[8];
    for (int h = 0; h < 8; ++h) o[h] = zero;

    const int srcbase = (lane & 48) + ((lane >> 4) << 2);  // shfl src for i=q*4+r
    const int cb = q ^ (c & 7);                            // QK chunk swizzle base
    const int prow = (wave * 16 + c) * 64;                 // sP row base (f16 elems)
    const int pwofs = (q & 1) * 4;                         // within-chunk write half

    __syncthreads();   // tile 0 staged

    int cur = 0;
    for (int jt = 0; jt < 16; ++jt) {
        const int jbase = jt * 64;
        const int nx = cur ^ 1;

        // stage jt+1 into buffer nx: issued now, drains at this iter's barrier
        if (jt < 15) {
            const char* gp = gYP + (size_t)(jt + 1) * 16384;
            const char* gt = gYT + (size_t)(jt + 1) * 16384;
            char* lp = (char*)&sTile[nx][0]    + wave * 1024;
            char* lt = (char*)&sTile[nx][8192] + wave * 1024;
            for (int i = 0; i < 2; ++i) {
                gld_lds16(gp + soff + i * 8192, lp + i * 8192);
                gld_lds16(gt + soff + i * 8192, lt + i * 8192);
            }
        }

        // QK swapped: D[j][i]; A-frags from swizzled sYP (conflict-free b128)
        f4v s[4];
        __builtin_amdgcn_s_setprio(1);
        for (int nt = 0; nt < 4; ++nt) {
            const _Float16* rp = &sTile[cur][0] + (nt * 16 + c) * 128;
            h8v f0 = *(const h8v*)(rp + ((cb ^ 0) << 3));
            h8v f1 = *(const h8v*)(rp + ((cb ^ 4) << 3));
            h8v f2 = *(const h8v*)(rp + ((cb ^ 8) << 3));
            h8v f3 = *(const h8v*)(rp + ((cb ^ 12) << 3));
            f4v acc = zero;
            acc = mfma_f16(f0, afrag[0], acc);
            acc = mfma_f16(f1, afrag[1], acc);
            acc = mfma_f16(f2, afrag[2], acc);
            acc = mfma_f16(f3, afrag[3], acc);
            s[nt] = acc;
        }
        __builtin_amdgcn_s_setprio(0);

        // mask: byte r of mw[nt] set -> j = nt*16 + q*4 + r is padding
        for (int nt = 0; nt < 4; ++nt)
            for (int r = 0; r < 4; ++r)
                if ((mw[nt] >> (r * 8)) & 0xFFu) s[nt][r] = -1e30f;

        // in-register row max (row i=c), then 2 cross-lane steps over q-group
        float mx = fmaxf(
            fmaxf(fmaxf(fmaxf(s[0][0], s[0][1]), fmaxf(s[0][2], s[0][3])),
                  fmaxf(fmaxf(s[1][0], s[1][1]), fmaxf(s[1][2], s[1][3]))),
            fmaxf(fmaxf(fmaxf(s[2][0], s[2][1]), fmaxf(s[2][2], s[2][3])),
                  fmaxf(fmaxf(s[3][0], s[3][1]), fmaxf(s[3][2], s[3][3]))));
        mx = fmaxf(mx, __shfl_xor(mx, 16, 64));
        mx = fmaxf(mx, __shfl_xor(mx, 32, 64));
        float mnew = fmaxf(m_s, mx);
        float alpha = __expf(m_s - mnew);   // expf(-inf)=0 on first tile
        m_s = mnew;

        // P in f16 (masked -> exactly 0); row-sum in-register + 2 cross-lane;
        // packed b64 write: chunk 2nt+(q>>1) at swizzled position ^(c&7)
        float rsum = 0.f;
        for (int nt = 0; nt < 4; ++nt) {
            h4v ph4;
            for (int r = 0; r < 4; ++r) {
                float p = ((mw[nt] >> (r * 8)) & 0xFFu) ? 0.f
                          : __expf(s[nt][r] - mnew);
                _Float16 ph = (_Float16)p;
                rsum += (float)ph;
                ph4[r] = ph;
            }
            int ck = (2 * nt + (q >> 1)) ^ (c & 7);
            *(h4v*)&sP[prow + ck * 8 + pwofs] = ph4;
        }
        rsum += __shfl_xor(rsum, 16, 64);
        rsum += __shfl_xor(rsum, 32, 64);
        l_s = l_s * alpha + rsum;

        // mask refill for jt+1 (old mw fully consumed above)
        if (jt < 15) {
            const int jn = jbase + 64;
            for (int nt = 0; nt < 4; ++nt)
                mw[nt] = *(const unsigned*)(nmask + mrow + jn + nt * 16 + q * 4);
        }

        // alpha for D-layout rows i=q*4+r (src lane in same 16-group)
        float aD0 = __shfl(alpha, srcbase + 0, 64);
        float aD1 = __shfl(alpha, srcbase + 1, 64);
        float aD2 = __shfl(alpha, srcbase + 2, 64);
        float aD3 = __shfl(alpha, srcbase + 3, 64);
        for (int h = 0; h < 8; ++h) {
            o[h][0] *= aD0; o[h][1] *= aD1; o[h][2] *= aD2; o[h][3] *= aD3;
        }

        // PV: A from wave-private swizzled sP (in-order DS), B from sYT
        __builtin_amdgcn_s_setprio(1);
        for (int k2 = 0; k2 < 2; ++k2) {
            h8v a = *(const h8v*)&sP[prow + (((k2 << 2) + q) ^ (c & 7)) * 8];
            const _Float16* yt = &sTile[cur][8192];
            for (int hb = 0; hb < 8; ++hb) {
                h8v bb = *(const h8v*)(yt + (hb * 16 + c) * 64
                                       + ((((k2 << 2) + q) ^ (c & 7)) << 3));
                o[hb] = mfma_f16(a, bb, o[hb]);
            }
        }
        __builtin_amdgcn_s_setprio(0);

        __syncthreads();   // drains stage(jt+1); all reads of cur complete
        cur = nx;
    }

    // l for D-layout rows i=q*4+r, then divide + store
    float lD[4];
    lD[0] = __shfl(l_s, srcbase + 0, 64);
    lD[1] = __shfl(l_s, srcbase + 1, 64);
    lD[2] = __shfl(l_s, srcbase + 2, 64);
    lD[3] = __shfl(l_s, srcbase + 3, 64);
    for (int h = 0; h < 8; ++h) {
        for (int r = 0; r < 4; ++r) {
            float v = o[h][r] / lD[r];
            out[(size_t)(mrow + ibase + wave * 16 + q * 4 + r) * 128 + h * 16 + c] = v;
        }
    }
}

// ---------------------------------------------------------------------------
extern "C" void kernel_launch(void* const* d_in, const int* in_sizes, int n_in,
                              void* d_out, int out_size, void* d_ws, size_t ws_size,
                              hipStream_t stream) {
    const float* x    = (const float*)d_in[0];  // [64,1024,128] fp32
    const float* y    = (const float*)d_in[1];
    const unsigned int* mraw = (const unsigned int*)d_in[2];
    const float* W    = (const float*)d_in[3];  // [128,128] fp32
    const float* bias = (const float*)d_in[4];  // [128] fp32
    float* out = (float*)d_out;                 // [64,1024,128] fp32

    // ws: nmask 64KB | Whsw 32KB | Wlsw 32KB | orw 4KB | YPsw 16MB | YTsw 16MB
    unsigned char* nmask = (unsigned char*)d_ws;
    short* Whsw = (short*)((char*)d_ws + 65536);
    short* Wlsw = Whsw + 16384;
    unsigned int* orw = (unsigned int*)((char*)d_ws + 131072);
    _Float16* YPsw = (_Float16*)((char*)d_ws + 135168);
    _Float16* YTsw = YPsw + (size_t)64 * 1024 * 128;

    prep_kernel<<<2, 1024, 0, stream>>>(mraw, orw, W, Whsw, Wlsw);
    proj_kernel<<<1024, BDIM, 0, stream>>>(y, Whsw, Wlsw, bias, orw,
                                           mraw, nmask, YPsw, YTsw);
    attn_kernel<<<512, 512, 0, stream>>>(x, Whsw, Wlsw, bias,
                                         YPsw, YTsw, nmask, out);
}